// Round 2
// baseline (3529.714 us; speedup 1.0000x reference)
//
#include <hip/hip_runtime.h>

static constexpr int NB   = 384;
static constexpr int SEQL = 256;
static constexpr int NROWS = NB * SEQL; // 98304

// ---------------------------------------------------------------------------
// Featurize + GRU layer-0 input projection:  X[(t*NB+b)*192 + j]
// ---------------------------------------------------------------------------
__global__ __launch_bounds__(192) void featproj_kernel(
    const float* __restrict__ x, const float* __restrict__ emb,
    const float* __restrict__ wih0, const float* __restrict__ bih0,
    float* __restrict__ X)
{
    __shared__ float F[32][33];
    const int tid = threadIdx.x;
    const int m0  = blockIdx.x * 32;

    if (tid < 96) {
        const int r   = tid & 31;
        const int grp = tid >> 5;          // 0,1,2 -> feature groups of 10
        const int m   = m0 + r;            // m = t*NB + b
        const int b   = m % NB;
        const int l   = m / NB;
        const float* xb = x + (size_t)b * (3 * SEQL);
        const float x0 = xb[l], x1 = xb[SEQL + l], x2 = xb[2 * SEQL + l];
        const bool is_angle = (b % 3) == 2;
        float o[10];
        if (is_angle) {
            if (grp < 2) {
                const float a = (grp == 0) ? x0 : x1;
                #pragma unroll
                for (int c = 0; c < 10; ++c) { float d = (float)(c + 1) - a; o[c] = __expf(-d * d); }
            } else {
                float t0 = 1.f, t1 = x2;
                o[0] = 1.f; o[1] = x2;
                #pragma unroll
                for (int c = 2; c < 10; ++c) { float t = 2.f * x2 * t1 - t0; o[c] = t; t0 = t1; t1 = t; }
            }
        } else {
            if (grp < 2) {
                const float xv = (grp == 0) ? x0 : x1;
                int idx = (int)xv; idx = idx < 0 ? 0 : (idx > 118 ? 118 : idx);
                #pragma unroll
                for (int c = 0; c < 10; ++c) o[c] = emb[idx * 10 + c];
            } else {
                #pragma unroll
                for (int c = 0; c < 10; ++c) { float d = (float)(c + 1) - x2; o[c] = __expf(-d * d); }
            }
        }
        #pragma unroll
        for (int c = 0; c < 10; ++c) F[r][grp * 10 + c] = o[c];
    }
    __syncthreads();

    float w[30];
    #pragma unroll
    for (int k = 0; k < 30; ++k) w[k] = wih0[tid * 30 + k];
    const float bj = bih0[tid];
    for (int r = 0; r < 32; ++r) {
        float acc = bj;
        #pragma unroll
        for (int k = 0; k < 30; ++k) acc += F[r][k] * w[k];
        X[(size_t)(m0 + r) * 192 + tid] = acc;
    }
}

// ---------------------------------------------------------------------------
// GRU recurrence. X holds precomputed xt@Wih.T + bih, row = t*NB + b.
// ---------------------------------------------------------------------------
__global__ __launch_bounds__(192) void gru_kernel(
    const float* __restrict__ X, const float* __restrict__ whh,
    const float* __restrict__ bhh, float* __restrict__ Y, int out_batch_major)
{
    const int b = blockIdx.x;
    const int j = threadIdx.x;
    __shared__ float h[64];
    __shared__ float gis[192], ghs[192];

    float w[64];
    #pragma unroll
    for (int k = 0; k < 64; ++k) w[k] = whh[j * 64 + k];
    const float bj = bhh[j];
    if (j < 64) h[j] = 0.f;
    __syncthreads();

    for (int t = 0; t < SEQL; ++t) {
        const float gi = X[((size_t)t * NB + b) * 192 + j];
        float gh = bj;
        #pragma unroll
        for (int k = 0; k < 64; ++k) gh += h[k] * w[k];
        gis[j] = gi; ghs[j] = gh;
        __syncthreads();
        if (j < 64) {
            const float r = 1.f / (1.f + __expf(-(gis[j] + ghs[j])));
            const float z = 1.f / (1.f + __expf(-(gis[64 + j] + ghs[64 + j])));
            const float n = tanhf(gis[128 + j] + r * ghs[128 + j]);
            const float hn = (1.f - z) * n + z * h[j];
            h[j] = hn;
            const size_t row = out_batch_major ? ((size_t)b * SEQL + t)
                                               : ((size_t)t * NB + b);
            Y[row * 64 + j] = hn;
        }
        __syncthreads();
    }
}

// ---------------------------------------------------------------------------
// Generic GEMM, K=64 fixed: C[m][n] = bias[n] + sum_k A[m][k]*W[n][k]
// ---------------------------------------------------------------------------
__global__ __launch_bounds__(256) void gemm64_kernel(
    const float* __restrict__ A, const float* __restrict__ W,
    const float* __restrict__ bias, float* __restrict__ C, int Ncols)
{
    __shared__ float As[128][68];
    __shared__ float WsT[64][68];
    const int tid = threadIdx.x;
    const int m0 = blockIdx.x * 128;
    const int n0 = blockIdx.y * 64;

    #pragma unroll
    for (int p = 0; p < 8; ++p) {
        const int i = tid + p * 256;
        const int r = i >> 4, c4 = i & 15;
        float4 v = *(const float4*)&A[((size_t)(m0 + r)) * 64 + c4 * 4];
        *(float4*)&As[r][c4 * 4] = v;
    }
    #pragma unroll
    for (int p = 0; p < 4; ++p) {
        const int i = tid + p * 256;
        const int n = i >> 4, c4 = i & 15;
        float4 v = *(const float4*)&W[((size_t)(n0 + n)) * 64 + c4 * 4];
        WsT[c4 * 4 + 0][n] = v.x; WsT[c4 * 4 + 1][n] = v.y;
        WsT[c4 * 4 + 2][n] = v.z; WsT[c4 * 4 + 3][n] = v.w;
    }
    __syncthreads();

    const int tx = tid & 15, ty = tid >> 4;
    float acc[8][4] = {};
    #pragma unroll
    for (int k4 = 0; k4 < 16; ++k4) {
        float4 w0 = *(const float4*)&WsT[k4 * 4 + 0][tx * 4];
        float4 w1 = *(const float4*)&WsT[k4 * 4 + 1][tx * 4];
        float4 w2 = *(const float4*)&WsT[k4 * 4 + 2][tx * 4];
        float4 w3 = *(const float4*)&WsT[k4 * 4 + 3][tx * 4];
        #pragma unroll
        for (int i = 0; i < 8; ++i) {
            float4 a = *(const float4*)&As[ty * 8 + i][k4 * 4];
            acc[i][0] += a.x * w0.x + a.y * w1.x + a.z * w2.x + a.w * w3.x;
            acc[i][1] += a.x * w0.y + a.y * w1.y + a.z * w2.y + a.w * w3.y;
            acc[i][2] += a.x * w0.z + a.y * w1.z + a.z * w2.z + a.w * w3.z;
            acc[i][3] += a.x * w0.w + a.y * w1.w + a.z * w2.w + a.w * w3.w;
        }
    }
    const float b0 = bias[n0 + tx * 4 + 0], b1 = bias[n0 + tx * 4 + 1];
    const float b2 = bias[n0 + tx * 4 + 2], b3 = bias[n0 + tx * 4 + 3];
    #pragma unroll
    for (int i = 0; i < 8; ++i) {
        float4 o;
        o.x = acc[i][0] + b0; o.y = acc[i][1] + b1;
        o.z = acc[i][2] + b2; o.w = acc[i][3] + b3;
        *(float4*)&C[((size_t)(m0 + ty * 8 + i)) * Ncols + n0 + tx * 4] = o;
    }
}

// ---------------------------------------------------------------------------
// Attention per (head, batch): online softmax, thread = query row.
// ---------------------------------------------------------------------------
__global__ __launch_bounds__(256) void attn_kernel(
    const float* __restrict__ QKV, float* __restrict__ O)
{
    const int hh = blockIdx.x;   // head
    const int b  = blockIdx.y;   // batch
    const int q  = threadIdx.x;  // query row
    const float scale = 0.17677669529663687f; // 1/sqrt(32)

    __shared__ float Ks[64][36];
    __shared__ float Vs[64][36];

    float qr[32];
    {
        const float* qrow = QKV + ((size_t)b * SEQL + q) * 192 + hh * 32;
        #pragma unroll
        for (int d4 = 0; d4 < 8; ++d4) {
            float4 v = *(const float4*)(qrow + d4 * 4);
            qr[d4 * 4 + 0] = v.x; qr[d4 * 4 + 1] = v.y;
            qr[d4 * 4 + 2] = v.z; qr[d4 * 4 + 3] = v.w;
        }
    }
    float m = -1e30f, l = 0.f;
    float o[32];
    #pragma unroll
    for (int d = 0; d < 32; ++d) o[d] = 0.f;

    for (int kc = 0; kc < 4; ++kc) {
        #pragma unroll
        for (int p = 0; p < 2; ++p) {
            const int i = threadIdx.x + p * 256;
            const int r = i >> 3, c4 = i & 7;
            const float* src = QKV + ((size_t)b * SEQL + kc * 64 + r) * 192 + 64 + hh * 32 + c4 * 4;
            *(float4*)&Ks[r][c4 * 4] = *(const float4*)src;
            *(float4*)&Vs[r][c4 * 4] = *(const float4*)(src + 64);
        }
        __syncthreads();
        for (int kk = 0; kk < 64; ++kk) {
            float s = 0.f;
            #pragma unroll
            for (int d = 0; d < 32; d += 4) {
                float4 kv = *(const float4*)&Ks[kk][d];
                s += qr[d] * kv.x + qr[d + 1] * kv.y + qr[d + 2] * kv.z + qr[d + 3] * kv.w;
            }
            s *= scale;
            const float mnew = fmaxf(m, s);
            const float corr = __expf(m - mnew);
            const float p    = __expf(s - mnew);
            l = l * corr + p;
            #pragma unroll
            for (int d = 0; d < 32; d += 4) {
                float4 vv = *(const float4*)&Vs[kk][d];
                o[d + 0] = o[d + 0] * corr + p * vv.x;
                o[d + 1] = o[d + 1] * corr + p * vv.y;
                o[d + 2] = o[d + 2] * corr + p * vv.z;
                o[d + 3] = o[d + 3] * corr + p * vv.w;
            }
            m = mnew;
        }
        __syncthreads();
    }
    const float inv = 1.f / l;
    float* orow = O + ((size_t)b * SEQL + q) * 64 + hh * 32;
    #pragma unroll
    for (int d4 = 0; d4 < 8; ++d4) {
        float4 v;
        v.x = o[d4 * 4 + 0] * inv; v.y = o[d4 * 4 + 1] * inv;
        v.z = o[d4 * 4 + 2] * inv; v.w = o[d4 * 4 + 3] * inv;
        *(float4*)(orow + d4 * 4) = v;
    }
}

// ---------------------------------------------------------------------------
// out = LN(A + B) * s + bb   (row-wise over 64), one wave per row
// ---------------------------------------------------------------------------
__global__ __launch_bounds__(256) void add_ln_kernel(
    const float* __restrict__ A, const float* __restrict__ B,
    const float* __restrict__ s, const float* __restrict__ bb,
    float* __restrict__ O)
{
    const size_t row = (size_t)blockIdx.x * 4 + (threadIdx.x >> 6);
    const int lane = threadIdx.x & 63;
    float v = A[row * 64 + lane] + B[row * 64 + lane];
    float sum = v;
    #pragma unroll
    for (int off = 32; off; off >>= 1) sum += __shfl_xor(sum, off);
    const float mean = sum * (1.f / 64.f);
    const float d = v - mean;
    float sq = d * d;
    #pragma unroll
    for (int off = 32; off; off >>= 1) sq += __shfl_xor(sq, off);
    const float var = sq * (1.f / 64.f);
    O[row * 64 + lane] = d * rsqrtf(var + 1e-5f) * s[lane] + bb[lane];
}

// ---------------------------------------------------------------------------
// Fused FFN v2: thread-per-row, weights via LDS broadcast.
// Out = relu(relu(X@W1.T + b1) @ W2.T + b2)
// 128 threads/block, 768 blocks (3/CU). Per thread: X row (64 regs) +
// output acc (64 regs); loop hidden n in chunks of 64 staged in LDS.
// All inner-loop LDS reads are wave-uniform (broadcast, conflict-free).
// ---------------------------------------------------------------------------
__global__ __launch_bounds__(128) void ffn_kernel(
    const float* __restrict__ Xin, const float* __restrict__ W1,
    const float* __restrict__ b1,  const float* __restrict__ W2,
    const float* __restrict__ b2,  float* __restrict__ Out)
{
    __shared__ float W1c[64][68];   // [n][k] chunk of W1, row-major
    __shared__ float W2cT[64][68];  // [n][j] chunk of W2, transposed
    __shared__ float b1c[64];

    const int tid = threadIdx.x;
    const size_t row = (size_t)blockIdx.x * 128 + tid;

    // X row into registers
    float4 xr[16];
    #pragma unroll
    for (int c = 0; c < 16; ++c)
        xr[c] = *(const float4*)&Xin[row * 64 + c * 4];

    float4 acc[16];
    #pragma unroll
    for (int j = 0; j < 16; ++j) acc[j] = make_float4(0.f, 0.f, 0.f, 0.f);

    for (int nc = 0; nc < 16; ++nc) {
        __syncthreads();  // previous chunk's reads done
        // stage W1 chunk: rows nc*64 .. +64, coalesced float4
        #pragma unroll
        for (int p = 0; p < 8; ++p) {
            const int i = tid + p * 128;
            const int n = i >> 4, c4 = i & 15;
            *(float4*)&W1c[n][c4 * 4] =
                *(const float4*)&W1[((size_t)(nc * 64 + n)) * 64 + c4 * 4];
        }
        // stage W2 chunk transposed: W2cT[l][j] = W2[j][nc*64+l]
        {
            const int l = tid & 63;
            const int jg = tid >> 6;   // 0..1
            #pragma unroll
            for (int jj = 0; jj < 32; ++jj) {
                const int j = jg * 32 + jj;
                W2cT[l][j] = W2[(size_t)j * 1024 + nc * 64 + l];
            }
        }
        if (tid < 64) b1c[tid] = b1[nc * 64 + tid];
        __syncthreads();

        #pragma unroll 2
        for (int nn = 0; nn < 64; ++nn) {
            // h = b1 + dot(Xrow, W1[n])  (4 partial chains)
            float h0 = b1c[nn], h1 = 0.f, h2 = 0.f, h3 = 0.f;
            #pragma unroll
            for (int c = 0; c < 16; c += 4) {
                float4 w0 = *(const float4*)&W1c[nn][(c + 0) * 4];
                float4 w1 = *(const float4*)&W1c[nn][(c + 1) * 4];
                float4 w2 = *(const float4*)&W1c[nn][(c + 2) * 4];
                float4 w3 = *(const float4*)&W1c[nn][(c + 3) * 4];
                h0 += xr[c + 0].x * w0.x + xr[c + 0].y * w0.y + xr[c + 0].z * w0.z + xr[c + 0].w * w0.w;
                h1 += xr[c + 1].x * w1.x + xr[c + 1].y * w1.y + xr[c + 1].z * w1.z + xr[c + 1].w * w1.w;
                h2 += xr[c + 2].x * w2.x + xr[c + 2].y * w2.y + xr[c + 2].z * w2.z + xr[c + 2].w * w2.w;
                h3 += xr[c + 3].x * w3.x + xr[c + 3].y * w3.y + xr[c + 3].z * w3.z + xr[c + 3].w * w3.w;
            }
            const float h = fmaxf((h0 + h1) + (h2 + h3), 0.f);
            #pragma unroll
            for (int j = 0; j < 16; ++j) {
                float4 w = *(const float4*)&W2cT[nn][j * 4];
                acc[j].x += h * w.x; acc[j].y += h * w.y;
                acc[j].z += h * w.z; acc[j].w += h * w.w;
            }
        }
    }

    #pragma unroll
    for (int j = 0; j < 16; ++j) {
        float4 o;
        o.x = fmaxf(acc[j].x + b2[j * 4 + 0], 0.f);
        o.y = fmaxf(acc[j].y + b2[j * 4 + 1], 0.f);
        o.z = fmaxf(acc[j].z + b2[j * 4 + 2], 0.f);
        o.w = fmaxf(acc[j].w + b2[j * 4 + 3], 0.f);
        *(float4*)&Out[row * 64 + j * 4] = o;
    }
}

// ---------------------------------------------------------------------------
// Head MLP over last timestep: 64 ->256 ->64 ->32 ->1 (silu x3)
// ---------------------------------------------------------------------------
__global__ __launch_bounds__(256) void head_kernel(
    const float* __restrict__ Hf,
    const float* __restrict__ fw1, const float* __restrict__ fb1,
    const float* __restrict__ fw2, const float* __restrict__ fb2,
    const float* __restrict__ fw3, const float* __restrict__ fb3,
    const float* __restrict__ fw4, const float* __restrict__ fb4,
    float* __restrict__ out)
{
    const int b = blockIdx.x;
    const int tid = threadIdx.x;
    __shared__ float t0[64], t1[256], t2[64], t3[32];
    if (tid < 64) t0[tid] = Hf[((size_t)b * SEQL + (SEQL - 1)) * 64 + tid];
    __syncthreads();
    {
        float acc = fb1[tid];
        #pragma unroll 4
        for (int k = 0; k < 64; ++k) acc += t0[k] * fw1[tid * 64 + k];
        t1[tid] = acc / (1.f + __expf(-acc));
    }
    __syncthreads();
    if (tid < 64) {
        float acc = fb2[tid];
        #pragma unroll 4
        for (int k = 0; k < 256; ++k) acc += t1[k] * fw2[tid * 256 + k];
        t2[tid] = acc / (1.f + __expf(-acc));
    }
    __syncthreads();
    if (tid < 32) {
        float acc = fb3[tid];
        #pragma unroll 4
        for (int k = 0; k < 64; ++k) acc += t2[k] * fw3[tid * 64 + k];
        t3[tid] = acc / (1.f + __expf(-acc));
    }
    __syncthreads();
    if (tid == 0) {
        float acc = fb4[0];
        #pragma unroll
        for (int k = 0; k < 32; ++k) acc += t3[k] * fw4[k];
        out[b] = acc;
    }
}

// ---------------------------------------------------------------------------
extern "C" void kernel_launch(void* const* d_in, const int* in_sizes, int n_in,
                              void* d_out, int out_size, void* d_ws, size_t ws_size,
                              hipStream_t stream) {
    const float* x     = (const float*)d_in[0];
    const float* emb   = (const float*)d_in[1];
    const float* wih0  = (const float*)d_in[2];
    const float* whh0  = (const float*)d_in[3];
    const float* bih0  = (const float*)d_in[4];
    const float* bhh0  = (const float*)d_in[5];
    const float* wih12 = (const float*)d_in[6];
    const float* whh12 = (const float*)d_in[7];
    const float* bih12 = (const float*)d_in[8];
    const float* bhh12 = (const float*)d_in[9];
    const float* in_w1 = (const float*)d_in[10];
    const float* in_b1 = (const float*)d_in[11];
    const float* out_w1= (const float*)d_in[12];
    const float* out_b1= (const float*)d_in[13];
    const float* in_w2 = (const float*)d_in[14];
    const float* in_b2 = (const float*)d_in[15];
    const float* out_w2= (const float*)d_in[16];
    const float* out_b2= (const float*)d_in[17];
    const float* ff_w1 = (const float*)d_in[18];
    const float* ff_b1 = (const float*)d_in[19];
    const float* ff_w2 = (const float*)d_in[20];
    const float* ff_b2 = (const float*)d_in[21];
    const float* ln1_s = (const float*)d_in[22];
    const float* ln1_b = (const float*)d_in[23];
    const float* ln2_s = (const float*)d_in[24];
    const float* ln2_b = (const float*)d_in[25];
    const float* ln3_s = (const float*)d_in[26];
    const float* ln3_b = (const float*)d_in[27];
    const float* ln4_s = (const float*)d_in[28];
    const float* ln4_b = (const float*)d_in[29];
    const float* fw1   = (const float*)d_in[30];
    const float* fb1   = (const float*)d_in[31];
    const float* fw2   = (const float*)d_in[32];
    const float* fb2   = (const float*)d_in[33];
    const float* fw3   = (const float*)d_in[34];
    const float* fb3   = (const float*)d_in[35];
    const float* fw4   = (const float*)d_in[36];
    const float* fb4   = (const float*)d_in[37];

    float* ws = (float*)d_ws;
    float* X  = ws;                       // 98304*192
    float* S0 = X  + (size_t)NROWS * 192; // 98304*64
    float* S1 = S0 + (size_t)NROWS * 64;
    float* S2 = S1 + (size_t)NROWS * 64;

    // ---- GRU stack ----
    featproj_kernel<<<NROWS / 32, 192, 0, stream>>>(x, emb, wih0, bih0, X);
    gru_kernel<<<NB, 192, 0, stream>>>(X, whh0, bhh0, S0, 0);
    gemm64_kernel<<<dim3(NROWS / 128, 3), 256, 0, stream>>>(S0, wih12, bih12, X, 192);
    gru_kernel<<<NB, 192, 0, stream>>>(X, whh12, bhh12, S1, 0);
    gemm64_kernel<<<dim3(NROWS / 128, 3), 256, 0, stream>>>(S1, wih12 + 192 * 64, bih12 + 192, X, 192);
    gru_kernel<<<NB, 192, 0, stream>>>(X, whh12 + 192 * 64, bhh12 + 192, S0, 1); // g (batch-major)

    // ---- Transformer block 1 ----
    gemm64_kernel<<<dim3(NROWS / 128, 3), 256, 0, stream>>>(S0, in_w1, in_b1, X, 192);
    attn_kernel<<<dim3(2, NB), 256, 0, stream>>>(X, S1);
    gemm64_kernel<<<dim3(NROWS / 128, 1), 256, 0, stream>>>(S1, out_w1, out_b1, S2, 64);
    add_ln_kernel<<<NROWS / 4, 256, 0, stream>>>(S0, S2, ln1_s, ln1_b, S1);      // h = LN(g + a)
    ffn_kernel<<<NROWS / 128, 128, 0, stream>>>(S1, ff_w1, ff_b1, ff_w2, ff_b2, S2);
    add_ln_kernel<<<NROWS / 4, 256, 0, stream>>>(S1, S2, ln2_s, ln2_b, S0);      // h = LN(h + ffn)

    // ---- Transformer block 2 ----
    gemm64_kernel<<<dim3(NROWS / 128, 3), 256, 0, stream>>>(S0, in_w2, in_b2, X, 192);
    attn_kernel<<<dim3(2, NB), 256, 0, stream>>>(X, S1);
    gemm64_kernel<<<dim3(NROWS / 128, 1), 256, 0, stream>>>(S1, out_w2, out_b2, S2, 64);
    add_ln_kernel<<<NROWS / 4, 256, 0, stream>>>(S2, S2, ln3_s, ln3_b, S1);      // h = LN(a + a)  (per reference!)
    ffn_kernel<<<NROWS / 128, 128, 0, stream>>>(S1, ff_w1, ff_b1, ff_w2, ff_b2, S2);
    add_ln_kernel<<<NROWS / 4, 256, 0, stream>>>(S1, S2, ln4_s, ln4_b, S0);      // h = LN(h + ffn)

    // ---- Head ----
    head_kernel<<<NB, 256, 0, stream>>>(S0, fw1, fb1, fw2, fb2, fw3, fb3, fw4, fb4,
                                        (float*)d_out);
    (void)in_sizes; (void)n_in; (void)out_size; (void)ws_size;
}

// Round 3
// 1312.473 us; speedup vs baseline: 2.6894x; 2.6894x over previous
//
#include <hip/hip_runtime.h>

static constexpr int NB   = 384;
static constexpr int SEQL = 256;
static constexpr int NROWS = NB * SEQL; // 98304

typedef short bf16x8 __attribute__((ext_vector_type(8)));
typedef float f32x4  __attribute__((ext_vector_type(4)));

union B8u {
    bf16x8 v;
    ushort us[8];
    uint4  q;
};

__device__ inline ushort f2bf(float f) {
    uint u = __float_as_uint(f);
    uint r = u + 0x7FFFu + ((u >> 16) & 1u);
    return (ushort)(r >> 16);
}

// split 8 consecutive floats (two float4) into bf16 hi + lo fragments
__device__ inline void split8(float4 a, float4 b, B8u& hi, B8u& lo) {
    float f[8] = {a.x, a.y, a.z, a.w, b.x, b.y, b.z, b.w};
    #pragma unroll
    for (int i = 0; i < 8; ++i) {
        ushort h = f2bf(f[i]);
        hi.us[i] = h;
        float fh = __uint_as_float(((uint)h) << 16);
        lo.us[i] = f2bf(f[i] - fh);
    }
}

// ---------------------------------------------------------------------------
// Pre-split weights: fp32 -> bf16 hi + bf16 lo
// ---------------------------------------------------------------------------
__global__ __launch_bounds__(256) void split_kernel(
    const float* __restrict__ src, ushort* __restrict__ hi,
    ushort* __restrict__ lo, int n)
{
    int i = blockIdx.x * 256 + threadIdx.x;
    if (i < n) {
        float f = src[i];
        ushort h = f2bf(f);
        hi[i] = h;
        float fh = __uint_as_float(((uint)h) << 16);
        lo[i] = f2bf(f - fh);
    }
}

// ---------------------------------------------------------------------------
// Featurize + GRU layer-0 input projection:  X[(t*NB+b)*192 + j]
// ---------------------------------------------------------------------------
__global__ __launch_bounds__(192) void featproj_kernel(
    const float* __restrict__ x, const float* __restrict__ emb,
    const float* __restrict__ wih0, const float* __restrict__ bih0,
    float* __restrict__ X)
{
    __shared__ float F[32][33];
    const int tid = threadIdx.x;
    const int m0  = blockIdx.x * 32;

    if (tid < 96) {
        const int r   = tid & 31;
        const int grp = tid >> 5;
        const int m   = m0 + r;
        const int b   = m % NB;
        const int l   = m / NB;
        const float* xb = x + (size_t)b * (3 * SEQL);
        const float x0 = xb[l], x1 = xb[SEQL + l], x2 = xb[2 * SEQL + l];
        const bool is_angle = (b % 3) == 2;
        float o[10];
        if (is_angle) {
            if (grp < 2) {
                const float a = (grp == 0) ? x0 : x1;
                #pragma unroll
                for (int c = 0; c < 10; ++c) { float d = (float)(c + 1) - a; o[c] = __expf(-d * d); }
            } else {
                float t0 = 1.f, t1 = x2;
                o[0] = 1.f; o[1] = x2;
                #pragma unroll
                for (int c = 2; c < 10; ++c) { float t = 2.f * x2 * t1 - t0; o[c] = t; t0 = t1; t1 = t; }
            }
        } else {
            if (grp < 2) {
                const float xv = (grp == 0) ? x0 : x1;
                int idx = (int)xv; idx = idx < 0 ? 0 : (idx > 118 ? 118 : idx);
                #pragma unroll
                for (int c = 0; c < 10; ++c) o[c] = emb[idx * 10 + c];
            } else {
                #pragma unroll
                for (int c = 0; c < 10; ++c) { float d = (float)(c + 1) - x2; o[c] = __expf(-d * d); }
            }
        }
        #pragma unroll
        for (int c = 0; c < 10; ++c) F[r][grp * 10 + c] = o[c];
    }
    __syncthreads();

    float w[30];
    #pragma unroll
    for (int k = 0; k < 30; ++k) w[k] = wih0[tid * 30 + k];
    const float bj = bih0[tid];
    for (int r = 0; r < 32; ++r) {
        float acc = bj;
        #pragma unroll
        for (int k = 0; k < 30; ++k) acc += F[r][k] * w[k];
        X[(size_t)(m0 + r) * 192 + tid] = acc;
    }
}

// ---------------------------------------------------------------------------
// GRU recurrence (unchanged)
// ---------------------------------------------------------------------------
__global__ __launch_bounds__(192) void gru_kernel(
    const float* __restrict__ X, const float* __restrict__ whh,
    const float* __restrict__ bhh, float* __restrict__ Y, int out_batch_major)
{
    const int b = blockIdx.x;
    const int j = threadIdx.x;
    __shared__ float h[64];
    __shared__ float gis[192], ghs[192];

    float w[64];
    #pragma unroll
    for (int k = 0; k < 64; ++k) w[k] = whh[j * 64 + k];
    const float bj = bhh[j];
    if (j < 64) h[j] = 0.f;
    __syncthreads();

    for (int t = 0; t < SEQL; ++t) {
        const float gi = X[((size_t)t * NB + b) * 192 + j];
        float gh = bj;
        #pragma unroll
        for (int k = 0; k < 64; ++k) gh += h[k] * w[k];
        gis[j] = gi; ghs[j] = gh;
        __syncthreads();
        if (j < 64) {
            const float r = 1.f / (1.f + __expf(-(gis[j] + ghs[j])));
            const float z = 1.f / (1.f + __expf(-(gis[64 + j] + ghs[64 + j])));
            const float n = tanhf(gis[128 + j] + r * ghs[128 + j]);
            const float hn = (1.f - z) * n + z * h[j];
            h[j] = hn;
            const size_t row = out_batch_major ? ((size_t)b * SEQL + t)
                                               : ((size_t)t * NB + b);
            Y[row * 64 + j] = hn;
        }
        __syncthreads();
    }
}

// ---------------------------------------------------------------------------
// MFMA GEMM, K=64: C[m][n] = bias[n] + A[m][0:64] . W[n][0:64]
// A fp32 global, W pre-split bf16 hi/lo. Exact via 3-pass split MFMA.
// 256 threads, BM=128 (32 rows/wave). No LDS, no barriers.
// ---------------------------------------------------------------------------
template<int NCOLS>
__global__ __launch_bounds__(256, 2) void gemm_mfma(
    const float* __restrict__ A, const ushort* __restrict__ Whi,
    const ushort* __restrict__ Wlo, const float* __restrict__ bias,
    float* __restrict__ C)
{
    const int tid = threadIdx.x;
    const int w   = tid >> 6;
    const int lane = tid & 63;
    const int c = lane & 15;
    const int g = lane >> 4;
    const int m0 = blockIdx.x * 128 + 32 * w;

    // A fragments (hi/lo) in registers
    B8u ah[2][2], al[2][2];
    #pragma unroll
    for (int rm = 0; rm < 2; ++rm) {
        const float* ap = A + (size_t)(m0 + 16 * rm + c) * 64;
        #pragma unroll
        for (int ks = 0; ks < 2; ++ks) {
            float4 v0 = *(const float4*)(ap + 32 * ks + 8 * g);
            float4 v1 = *(const float4*)(ap + 32 * ks + 8 * g + 4);
            split8(v0, v1, ah[rm][ks], al[rm][ks]);
        }
    }

    f32x4 acc[NCOLS / 16][2];
    #pragma unroll
    for (int nt = 0; nt < NCOLS / 16; ++nt) {
        float bv = bias[16 * nt + c];
        #pragma unroll
        for (int rm = 0; rm < 2; ++rm)
            acc[nt][rm] = (f32x4){bv, bv, bv, bv};
    }

    #pragma unroll
    for (int nt = 0; nt < NCOLS / 16; ++nt) {
        B8u wh[2], wl[2];
        #pragma unroll
        for (int ks = 0; ks < 2; ++ks) {
            size_t off = (size_t)(16 * nt + c) * 64 + 32 * ks + 8 * g;
            wh[ks].q = *(const uint4*)(Whi + off);
            wl[ks].q = *(const uint4*)(Wlo + off);
        }
        #pragma unroll
        for (int rm = 0; rm < 2; ++rm)
            #pragma unroll
            for (int ks = 0; ks < 2; ++ks) {
                acc[nt][rm] = __builtin_amdgcn_mfma_f32_16x16x32_bf16(ah[rm][ks].v, wh[ks].v, acc[nt][rm], 0, 0, 0);
                acc[nt][rm] = __builtin_amdgcn_mfma_f32_16x16x32_bf16(al[rm][ks].v, wh[ks].v, acc[nt][rm], 0, 0, 0);
                acc[nt][rm] = __builtin_amdgcn_mfma_f32_16x16x32_bf16(ah[rm][ks].v, wl[ks].v, acc[nt][rm], 0, 0, 0);
            }
    }

    #pragma unroll
    for (int nt = 0; nt < NCOLS / 16; ++nt)
        #pragma unroll
        for (int rm = 0; rm < 2; ++rm)
            #pragma unroll
            for (int reg = 0; reg < 4; ++reg) {
                int row = m0 + 16 * rm + 4 * g + reg;
                C[(size_t)row * NCOLS + 16 * nt + c] = acc[nt][rm][reg];
            }
}

// ---------------------------------------------------------------------------
// Fused FFN via split-bf16 MFMA.
// Out = relu(relu(X@W1.T + b1) @ W2.T + b2), hidden 1024 chunked by 64.
// GEMM1 computed swapped (H^T = W1c . X^T) so C-fragments pack (b64) into
// the [row][n] LDS layout GEMM2's A-fragments read (b128). H is wave-private.
// ---------------------------------------------------------------------------
__global__ __launch_bounds__(256, 2) void ffn_mfma(
    const float* __restrict__ Xin,
    const ushort* __restrict__ W1hi, const ushort* __restrict__ W1lo,
    const ushort* __restrict__ W2hi, const ushort* __restrict__ W2lo,
    const float* __restrict__ b1, const float* __restrict__ b2,
    float* __restrict__ Out)
{
    __shared__ __align__(16) ushort sW1h[64 * 72], sW1l[64 * 72];
    __shared__ __align__(16) ushort sW2h[64 * 72], sW2l[64 * 72];
    __shared__ __align__(16) ushort sHh[128 * 72], sHl[128 * 72];
    __shared__ float sb1[64];

    const int tid = threadIdx.x;
    const int w   = tid >> 6;
    const int lane = tid & 63;
    const int c = lane & 15;
    const int g = lane >> 4;
    const int r0 = blockIdx.x * 128;

    // X fragments (hi/lo), chunk-invariant, kept in registers
    B8u xh[2][2], xl[2][2];
    #pragma unroll
    for (int rm = 0; rm < 2; ++rm) {
        const float* ap = Xin + (size_t)(r0 + 32 * w + 16 * rm + c) * 64;
        #pragma unroll
        for (int ks = 0; ks < 2; ++ks) {
            float4 v0 = *(const float4*)(ap + 32 * ks + 8 * g);
            float4 v1 = *(const float4*)(ap + 32 * ks + 8 * g + 4);
            split8(v0, v1, xh[rm][ks], xl[rm][ks]);
        }
    }

    // acc2 initialized with b2 (per-lane column)
    f32x4 acc2[4][2];
    #pragma unroll
    for (int jt = 0; jt < 4; ++jt) {
        float bv = b2[16 * jt + c];
        #pragma unroll
        for (int mt = 0; mt < 2; ++mt)
            acc2[jt][mt] = (f32x4){bv, bv, bv, bv};
    }

    for (int nc = 0; nc < 16; ++nc) {
        __syncthreads();
        // stage pre-split W1/W2 chunks (bf16, straight copy, b128)
        {
            const int n = tid >> 2, s = tid & 3;
            size_t s1 = (size_t)(nc * 64 + n) * 64 + s * 16;
            size_t s2 = (size_t)n * 1024 + nc * 64 + s * 16;
            int d = n * 72 + s * 16;
            *(uint4*)&sW1h[d]     = *(const uint4*)(W1hi + s1);
            *(uint4*)&sW1h[d + 8] = *(const uint4*)(W1hi + s1 + 8);
            *(uint4*)&sW1l[d]     = *(const uint4*)(W1lo + s1);
            *(uint4*)&sW1l[d + 8] = *(const uint4*)(W1lo + s1 + 8);
            *(uint4*)&sW2h[d]     = *(const uint4*)(W2hi + s2);
            *(uint4*)&sW2h[d + 8] = *(const uint4*)(W2hi + s2 + 8);
            *(uint4*)&sW2l[d]     = *(const uint4*)(W2lo + s2);
            *(uint4*)&sW2l[d + 8] = *(const uint4*)(W2lo + s2 + 8);
            if (tid < 64) sb1[tid] = b1[nc * 64 + tid];
        }
        __syncthreads();

        // ---- GEMM1: H^T = W1c . X^T  (M = n-chunk, N = our 32 rows) ----
        f32x4 acc1[4][2];
        #pragma unroll
        for (int jm = 0; jm < 4; ++jm) {
            float b0 = sb1[16 * jm + 4 * g + 0];
            float b1v = sb1[16 * jm + 4 * g + 1];
            float b2v = sb1[16 * jm + 4 * g + 2];
            float b3v = sb1[16 * jm + 4 * g + 3];
            #pragma unroll
            for (int rm = 0; rm < 2; ++rm)
                acc1[jm][rm] = (f32x4){b0, b1v, b2v, b3v};
        }
        #pragma unroll
        for (int jm = 0; jm < 4; ++jm) {
            B8u w1h[2], w1l[2];
            #pragma unroll
            for (int ks = 0; ks < 2; ++ks) {
                int off = (16 * jm + c) * 72 + 32 * ks + 8 * g;
                w1h[ks].q = *(const uint4*)&sW1h[off];
                w1l[ks].q = *(const uint4*)&sW1l[off];
            }
            #pragma unroll
            for (int rm = 0; rm < 2; ++rm)
                #pragma unroll
                for (int ks = 0; ks < 2; ++ks) {
                    acc1[jm][rm] = __builtin_amdgcn_mfma_f32_16x16x32_bf16(w1h[ks].v, xh[rm][ks].v, acc1[jm][rm], 0, 0, 0);
                    acc1[jm][rm] = __builtin_amdgcn_mfma_f32_16x16x32_bf16(w1l[ks].v, xh[rm][ks].v, acc1[jm][rm], 0, 0, 0);
                    acc1[jm][rm] = __builtin_amdgcn_mfma_f32_16x16x32_bf16(w1h[ks].v, xl[rm][ks].v, acc1[jm][rm], 0, 0, 0);
                }
        }
        // relu + split + pack; write H (wave-private rows) to LDS
        #pragma unroll
        for (int jm = 0; jm < 4; ++jm)
            #pragma unroll
            for (int rm = 0; rm < 2; ++rm) {
                ushort hh[4], hl[4];
                #pragma unroll
                for (int reg = 0; reg < 4; ++reg) {
                    float hv = fmaxf(acc1[jm][rm][reg], 0.f);
                    ushort h = f2bf(hv);
                    hh[reg] = h;
                    float fh = __uint_as_float(((uint)h) << 16);
                    hl[reg] = f2bf(hv - fh);
                }
                int el = (32 * w + 16 * rm + c) * 72 + 16 * jm + 4 * g;
                *(uint2*)&sHh[el] = make_uint2((uint)hh[0] | ((uint)hh[1] << 16),
                                               (uint)hh[2] | ((uint)hh[3] << 16));
                *(uint2*)&sHl[el] = make_uint2((uint)hl[0] | ((uint)hl[1] << 16),
                                               (uint)hl[2] | ((uint)hl[3] << 16));
            }
        // same-wave write->read; ensure completion
        asm volatile("s_waitcnt lgkmcnt(0)" ::: "memory");
        __builtin_amdgcn_sched_barrier(0);

        // ---- GEMM2 partial: acc2 += H . W2c^T ----
        #pragma unroll
        for (int ks = 0; ks < 2; ++ks) {
            B8u ahh[2], ahl[2], bwh[4], bwl[4];
            #pragma unroll
            for (int mt = 0; mt < 2; ++mt) {
                int el = (32 * w + 16 * mt + c) * 72 + 32 * ks + 8 * g;
                ahh[mt].q = *(const uint4*)&sHh[el];
                ahl[mt].q = *(const uint4*)&sHl[el];
            }
            #pragma unroll
            for (int jt = 0; jt < 4; ++jt) {
                int el = (16 * jt + c) * 72 + 32 * ks + 8 * g;
                bwh[jt].q = *(const uint4*)&sW2h[el];
                bwl[jt].q = *(const uint4*)&sW2l[el];
            }
            #pragma unroll
            for (int jt = 0; jt < 4; ++jt)
                #pragma unroll
                for (int mt = 0; mt < 2; ++mt) {
                    acc2[jt][mt] = __builtin_amdgcn_mfma_f32_16x16x32_bf16(ahh[mt].v, bwh[jt].v, acc2[jt][mt], 0, 0, 0);
                    acc2[jt][mt] = __builtin_amdgcn_mfma_f32_16x16x32_bf16(ahl[mt].v, bwh[jt].v, acc2[jt][mt], 0, 0, 0);
                    acc2[jt][mt] = __builtin_amdgcn_mfma_f32_16x16x32_bf16(ahh[mt].v, bwl[jt].v, acc2[jt][mt], 0, 0, 0);
                }
        }
    }

    #pragma unroll
    for (int jt = 0; jt < 4; ++jt)
        #pragma unroll
        for (int mt = 0; mt < 2; ++mt)
            #pragma unroll
            for (int reg = 0; reg < 4; ++reg) {
                int row = r0 + 32 * w + 16 * mt + 4 * g + reg;
                Out[(size_t)row * 64 + 16 * jt + c] = fmaxf(acc2[jt][mt][reg], 0.f);
            }
}

// ---------------------------------------------------------------------------
// Attention per (head, batch): online softmax, thread = query row.
// ---------------------------------------------------------------------------
__global__ __launch_bounds__(256) void attn_kernel(
    const float* __restrict__ QKV, float* __restrict__ O)
{
    const int hh = blockIdx.x;
    const int b  = blockIdx.y;
    const int q  = threadIdx.x;
    const float scale = 0.17677669529663687f;

    __shared__ float Ks[64][36];
    __shared__ float Vs[64][36];

    float qr[32];
    {
        const float* qrow = QKV + ((size_t)b * SEQL + q) * 192 + hh * 32;
        #pragma unroll
        for (int d4 = 0; d4 < 8; ++d4) {
            float4 v = *(const float4*)(qrow + d4 * 4);
            qr[d4 * 4 + 0] = v.x; qr[d4 * 4 + 1] = v.y;
            qr[d4 * 4 + 2] = v.z; qr[d4 * 4 + 3] = v.w;
        }
    }
    float m = -1e30f, l = 0.f;
    float o[32];
    #pragma unroll
    for (int d = 0; d < 32; ++d) o[d] = 0.f;

    for (int kc = 0; kc < 4; ++kc) {
        #pragma unroll
        for (int p = 0; p < 2; ++p) {
            const int i = threadIdx.x + p * 256;
            const int r = i >> 3, c4 = i & 7;
            const float* src = QKV + ((size_t)b * SEQL + kc * 64 + r) * 192 + 64 + hh * 32 + c4 * 4;
            *(float4*)&Ks[r][c4 * 4] = *(const float4*)src;
            *(float4*)&Vs[r][c4 * 4] = *(const float4*)(src + 64);
        }
        __syncthreads();
        for (int kk = 0; kk < 64; ++kk) {
            float s = 0.f;
            #pragma unroll
            for (int d = 0; d < 32; d += 4) {
                float4 kv = *(const float4*)&Ks[kk][d];
                s += qr[d] * kv.x + qr[d + 1] * kv.y + qr[d + 2] * kv.z + qr[d + 3] * kv.w;
            }
            s *= scale;
            const float mnew = fmaxf(m, s);
            const float corr = __expf(m - mnew);
            const float p    = __expf(s - mnew);
            l = l * corr + p;
            #pragma unroll
            for (int d = 0; d < 32; d += 4) {
                float4 vv = *(const float4*)&Vs[kk][d];
                o[d + 0] = o[d + 0] * corr + p * vv.x;
                o[d + 1] = o[d + 1] * corr + p * vv.y;
                o[d + 2] = o[d + 2] * corr + p * vv.z;
                o[d + 3] = o[d + 3] * corr + p * vv.w;
            }
            m = mnew;
        }
        __syncthreads();
    }
    const float inv = 1.f / l;
    float* orow = O + ((size_t)b * SEQL + q) * 64 + hh * 32;
    #pragma unroll
    for (int d4 = 0; d4 < 8; ++d4) {
        float4 v;
        v.x = o[d4 * 4 + 0] * inv; v.y = o[d4 * 4 + 1] * inv;
        v.z = o[d4 * 4 + 2] * inv; v.w = o[d4 * 4 + 3] * inv;
        *(float4*)(orow + d4 * 4) = v;
    }
}

// ---------------------------------------------------------------------------
// out = LN(A + B) * s + bb   (row-wise over 64), one wave per row
// ---------------------------------------------------------------------------
__global__ __launch_bounds__(256) void add_ln_kernel(
    const float* __restrict__ A, const float* __restrict__ B,
    const float* __restrict__ s, const float* __restrict__ bb,
    float* __restrict__ O)
{
    const size_t row = (size_t)blockIdx.x * 4 + (threadIdx.x >> 6);
    const int lane = threadIdx.x & 63;
    float v = A[row * 64 + lane] + B[row * 64 + lane];
    float sum = v;
    #pragma unroll
    for (int off = 32; off; off >>= 1) sum += __shfl_xor(sum, off);
    const float mean = sum * (1.f / 64.f);
    const float d = v - mean;
    float sq = d * d;
    #pragma unroll
    for (int off = 32; off; off >>= 1) sq += __shfl_xor(sq, off);
    const float var = sq * (1.f / 64.f);
    O[row * 64 + lane] = d * rsqrtf(var + 1e-5f) * s[lane] + bb[lane];
}

// ---------------------------------------------------------------------------
// Head MLP over last timestep: 64 ->256 ->64 ->32 ->1 (silu x3)
// ---------------------------------------------------------------------------
__global__ __launch_bounds__(256) void head_kernel(
    const float* __restrict__ Hf,
    const float* __restrict__ fw1, const float* __restrict__ fb1,
    const float* __restrict__ fw2, const float* __restrict__ fb2,
    const float* __restrict__ fw3, const float* __restrict__ fb3,
    const float* __restrict__ fw4, const float* __restrict__ fb4,
    float* __restrict__ out)
{
    const int b = blockIdx.x;
    const int tid = threadIdx.x;
    __shared__ float t0[64], t1[256], t2[64], t3[32];
    if (tid < 64) t0[tid] = Hf[((size_t)b * SEQL + (SEQL - 1)) * 64 + tid];
    __syncthreads();
    {
        float acc = fb1[tid];
        #pragma unroll 4
        for (int k = 0; k < 64; ++k) acc += t0[k] * fw1[tid * 64 + k];
        t1[tid] = acc / (1.f + __expf(-acc));
    }
    __syncthreads();
    if (tid < 64) {
        float acc = fb2[tid];
        #pragma unroll 4
        for (int k = 0; k < 256; ++k) acc += t1[k] * fw2[tid * 256 + k];
        t2[tid] = acc / (1.f + __expf(-acc));
    }
    __syncthreads();
    if (tid < 32) {
        float acc = fb3[tid];
        #pragma unroll 4
        for (int k = 0; k < 64; ++k) acc += t2[k] * fw3[tid * 64 + k];
        t3[tid] = acc / (1.f + __expf(-acc));
    }
    __syncthreads();
    if (tid == 0) {
        float acc = fb4[0];
        #pragma unroll
        for (int k = 0; k < 32; ++k) acc += t3[k] * fw4[k];
        out[b] = acc;
    }
}

// ---------------------------------------------------------------------------
extern "C" void kernel_launch(void* const* d_in, const int* in_sizes, int n_in,
                              void* d_out, int out_size, void* d_ws, size_t ws_size,
                              hipStream_t stream) {
    const float* x     = (const float*)d_in[0];
    const float* emb   = (const float*)d_in[1];
    const float* wih0  = (const float*)d_in[2];
    const float* whh0  = (const float*)d_in[3];
    const float* bih0  = (const float*)d_in[4];
    const float* bhh0  = (const float*)d_in[5];
    const float* wih12 = (const float*)d_in[6];
    const float* whh12 = (const float*)d_in[7];
    const float* bih12 = (const float*)d_in[8];
    const float* bhh12 = (const float*)d_in[9];
    const float* in_w1 = (const float*)d_in[10];
    const float* in_b1 = (const float*)d_in[11];
    const float* out_w1= (const float*)d_in[12];
    const float* out_b1= (const float*)d_in[13];
    const float* in_w2 = (const float*)d_in[14];
    const float* in_b2 = (const float*)d_in[15];
    const float* out_w2= (const float*)d_in[16];
    const float* out_b2= (const float*)d_in[17];
    const float* ff_w1 = (const float*)d_in[18];
    const float* ff_b1 = (const float*)d_in[19];
    const float* ff_w2 = (const float*)d_in[20];
    const float* ff_b2 = (const float*)d_in[21];
    const float* ln1_s = (const float*)d_in[22];
    const float* ln1_b = (const float*)d_in[23];
    const float* ln2_s = (const float*)d_in[24];
    const float* ln2_b = (const float*)d_in[25];
    const float* ln3_s = (const float*)d_in[26];
    const float* ln3_b = (const float*)d_in[27];
    const float* ln4_s = (const float*)d_in[28];
    const float* ln4_b = (const float*)d_in[29];
    const float* fw1   = (const float*)d_in[30];
    const float* fb1   = (const float*)d_in[31];
    const float* fw2   = (const float*)d_in[32];
    const float* fb2   = (const float*)d_in[33];
    const float* fw3   = (const float*)d_in[34];
    const float* fb3   = (const float*)d_in[35];
    const float* fw4   = (const float*)d_in[36];
    const float* fb4   = (const float*)d_in[37];

    float* ws = (float*)d_ws;
    float* X  = ws;                       // 98304*192
    float* S0 = X  + (size_t)NROWS * 192; // 98304*64
    float* S1 = S0 + (size_t)NROWS * 64;
    float* S2 = S1 + (size_t)NROWS * 64;

    // bf16 split-weight region after the fp32 buffers
    ushort* bf = (ushort*)(S2 + (size_t)NROWS * 64);
    ushort* ffw1hi = bf;               // 65536
    ushort* ffw1lo = ffw1hi + 65536;
    ushort* ffw2hi = ffw1lo + 65536;   // 65536
    ushort* ffw2lo = ffw2hi + 65536;
    ushort* wghi   = ffw2lo + 65536;   // 24576 (2 layers x 192 x 64)
    ushort* wglo   = wghi + 24576;
    ushort* q1hi   = wglo + 24576;     // 12288
    ushort* q1lo   = q1hi + 12288;
    ushort* q2hi   = q1lo + 12288;
    ushort* q2lo   = q2hi + 12288;
    ushort* o1hi   = q2lo + 12288;     // 4096
    ushort* o1lo   = o1hi + 4096;
    ushort* o2hi   = o1lo + 4096;
    ushort* o2lo   = o2hi + 4096;

    // ---- pre-split all MFMA weights ----
    split_kernel<<<65536 / 256, 256, 0, stream>>>(ff_w1, ffw1hi, ffw1lo, 65536);
    split_kernel<<<65536 / 256, 256, 0, stream>>>(ff_w2, ffw2hi, ffw2lo, 65536);
    split_kernel<<<24576 / 256, 256, 0, stream>>>(wih12, wghi, wglo, 24576);
    split_kernel<<<12288 / 256, 256, 0, stream>>>(in_w1, q1hi, q1lo, 12288);
    split_kernel<<<12288 / 256, 256, 0, stream>>>(in_w2, q2hi, q2lo, 12288);
    split_kernel<<<4096 / 256, 256, 0, stream>>>(out_w1, o1hi, o1lo, 4096);
    split_kernel<<<4096 / 256, 256, 0, stream>>>(out_w2, o2hi, o2lo, 4096);

    // ---- GRU stack ----
    featproj_kernel<<<NROWS / 32, 192, 0, stream>>>(x, emb, wih0, bih0, X);
    gru_kernel<<<NB, 192, 0, stream>>>(X, whh0, bhh0, S0, 0);
    gemm_mfma<192><<<NROWS / 128, 256, 0, stream>>>(S0, wghi, wglo, bih12, X);
    gru_kernel<<<NB, 192, 0, stream>>>(X, whh12, bhh12, S1, 0);
    gemm_mfma<192><<<NROWS / 128, 256, 0, stream>>>(S1, wghi + 12288, wglo + 12288, bih12 + 192, X);
    gru_kernel<<<NB, 192, 0, stream>>>(X, whh12 + 192 * 64, bhh12 + 192, S0, 1); // g (batch-major)

    // ---- Transformer block 1 ----
    gemm_mfma<192><<<NROWS / 128, 256, 0, stream>>>(S0, q1hi, q1lo, in_b1, X);
    attn_kernel<<<dim3(2, NB), 256, 0, stream>>>(X, S1);
    gemm_mfma<64><<<NROWS / 128, 256, 0, stream>>>(S1, o1hi, o1lo, out_b1, S2);
    add_ln_kernel<<<NROWS / 4, 256, 0, stream>>>(S0, S2, ln1_s, ln1_b, S1);      // h = LN(g + a)
    ffn_mfma<<<NROWS / 128, 256, 0, stream>>>(S1, ffw1hi, ffw1lo, ffw2hi, ffw2lo, ff_b1, ff_b2, S2);
    add_ln_kernel<<<NROWS / 4, 256, 0, stream>>>(S1, S2, ln2_s, ln2_b, S0);      // h = LN(h + ffn)

    // ---- Transformer block 2 ----
    gemm_mfma<192><<<NROWS / 128, 256, 0, stream>>>(S0, q2hi, q2lo, in_b2, X);
    attn_kernel<<<dim3(2, NB), 256, 0, stream>>>(X, S1);
    gemm_mfma<64><<<NROWS / 128, 256, 0, stream>>>(S1, o2hi, o2lo, out_b2, S2);
    add_ln_kernel<<<NROWS / 4, 256, 0, stream>>>(S2, S2, ln3_s, ln3_b, S1);      // h = LN(a + a)  (per reference!)
    ffn_mfma<<<NROWS / 128, 256, 0, stream>>>(S1, ffw1hi, ffw1lo, ffw2hi, ffw2lo, ff_b1, ff_b2, S2);
    add_ln_kernel<<<NROWS / 4, 256, 0, stream>>>(S1, S2, ln4_s, ln4_b, S0);      // h = LN(h + ffn)

    // ---- Head ----
    head_kernel<<<NB, 256, 0, stream>>>(S0, fw1, fb1, fw2, fb2, fw3, fb3, fw4, fb4,
                                        (float*)d_out);
    (void)in_sizes; (void)n_in; (void)out_size; (void)ws_size;
}

// Round 4
// 1057.119 us; speedup vs baseline: 3.3390x; 1.2416x over previous
//
#include <hip/hip_runtime.h>

static constexpr int NB   = 384;
static constexpr int SEQL = 256;
static constexpr int NROWS = NB * SEQL; // 98304

typedef short bf16x8 __attribute__((ext_vector_type(8)));
typedef float f32x4  __attribute__((ext_vector_type(4)));

union B8u {
    bf16x8 v;
    ushort us[8];
    uint4  q;
};

__device__ inline ushort f2bf(float f) {
    uint u = __float_as_uint(f);
    uint r = u + 0x7FFFu + ((u >> 16) & 1u);
    return (ushort)(r >> 16);
}

// split 8 consecutive floats (two float4) into bf16 hi + lo fragments
__device__ inline void split8(float4 a, float4 b, B8u& hi, B8u& lo) {
    float f[8] = {a.x, a.y, a.z, a.w, b.x, b.y, b.z, b.w};
    #pragma unroll
    for (int i = 0; i < 8; ++i) {
        ushort h = f2bf(f[i]);
        hi.us[i] = h;
        float fh = __uint_as_float(((uint)h) << 16);
        lo.us[i] = f2bf(f[i] - fh);
    }
}

// ---------------------------------------------------------------------------
// Pre-split weights: fp32 -> bf16 hi + bf16 lo
// ---------------------------------------------------------------------------
__global__ __launch_bounds__(256) void split_kernel(
    const float* __restrict__ src, ushort* __restrict__ hi,
    ushort* __restrict__ lo, int n)
{
    int i = blockIdx.x * 256 + threadIdx.x;
    if (i < n) {
        float f = src[i];
        ushort h = f2bf(f);
        hi[i] = h;
        float fh = __uint_as_float(((uint)h) << 16);
        lo[i] = f2bf(f - fh);
    }
}

// ---------------------------------------------------------------------------
// Featurize + GRU layer-0 input projection:  X[(t*NB+b)*192 + j]
// ---------------------------------------------------------------------------
__global__ __launch_bounds__(192) void featproj_kernel(
    const float* __restrict__ x, const float* __restrict__ emb,
    const float* __restrict__ wih0, const float* __restrict__ bih0,
    float* __restrict__ X)
{
    __shared__ float F[32][33];
    const int tid = threadIdx.x;
    const int m0  = blockIdx.x * 32;

    if (tid < 96) {
        const int r   = tid & 31;
        const int grp = tid >> 5;
        const int m   = m0 + r;
        const int b   = m % NB;
        const int l   = m / NB;
        const float* xb = x + (size_t)b * (3 * SEQL);
        const float x0 = xb[l], x1 = xb[SEQL + l], x2 = xb[2 * SEQL + l];
        const bool is_angle = (b % 3) == 2;
        float o[10];
        if (is_angle) {
            if (grp < 2) {
                const float a = (grp == 0) ? x0 : x1;
                #pragma unroll
                for (int c = 0; c < 10; ++c) { float d = (float)(c + 1) - a; o[c] = __expf(-d * d); }
            } else {
                float t0 = 1.f, t1 = x2;
                o[0] = 1.f; o[1] = x2;
                #pragma unroll
                for (int c = 2; c < 10; ++c) { float t = 2.f * x2 * t1 - t0; o[c] = t; t0 = t1; t1 = t; }
            }
        } else {
            if (grp < 2) {
                const float xv = (grp == 0) ? x0 : x1;
                int idx = (int)xv; idx = idx < 0 ? 0 : (idx > 118 ? 118 : idx);
                #pragma unroll
                for (int c = 0; c < 10; ++c) o[c] = emb[idx * 10 + c];
            } else {
                #pragma unroll
                for (int c = 0; c < 10; ++c) { float d = (float)(c + 1) - x2; o[c] = __expf(-d * d); }
            }
        }
        #pragma unroll
        for (int c = 0; c < 10; ++c) F[r][grp * 10 + c] = o[c];
    }
    __syncthreads();

    float w[30];
    #pragma unroll
    for (int k = 0; k < 30; ++k) w[k] = wih0[tid * 30 + k];
    const float bj = bih0[tid];
    for (int r = 0; r < 32; ++r) {
        float acc = bj;
        #pragma unroll
        for (int k = 0; k < 30; ++k) acc += F[r][k] * w[k];
        X[(size_t)(m0 + r) * 192 + tid] = acc;
    }
}

// ---------------------------------------------------------------------------
// GRU recurrence (unchanged)
// ---------------------------------------------------------------------------
__global__ __launch_bounds__(192) void gru_kernel(
    const float* __restrict__ X, const float* __restrict__ whh,
    const float* __restrict__ bhh, float* __restrict__ Y, int out_batch_major)
{
    const int b = blockIdx.x;
    const int j = threadIdx.x;
    __shared__ float h[64];
    __shared__ float gis[192], ghs[192];

    float w[64];
    #pragma unroll
    for (int k = 0; k < 64; ++k) w[k] = whh[j * 64 + k];
    const float bj = bhh[j];
    if (j < 64) h[j] = 0.f;
    __syncthreads();

    for (int t = 0; t < SEQL; ++t) {
        const float gi = X[((size_t)t * NB + b) * 192 + j];
        float gh = bj;
        #pragma unroll
        for (int k = 0; k < 64; ++k) gh += h[k] * w[k];
        gis[j] = gi; ghs[j] = gh;
        __syncthreads();
        if (j < 64) {
            const float r = 1.f / (1.f + __expf(-(gis[j] + ghs[j])));
            const float z = 1.f / (1.f + __expf(-(gis[64 + j] + ghs[64 + j])));
            const float n = tanhf(gis[128 + j] + r * ghs[128 + j]);
            const float hn = (1.f - z) * n + z * h[j];
            h[j] = hn;
            const size_t row = out_batch_major ? ((size_t)b * SEQL + t)
                                               : ((size_t)t * NB + b);
            Y[row * 64 + j] = hn;
        }
        __syncthreads();
    }
}

// ---------------------------------------------------------------------------
// MFMA GEMM, K=64 (unchanged from round 3)
// ---------------------------------------------------------------------------
template<int NCOLS>
__global__ __launch_bounds__(256, 2) void gemm_mfma(
    const float* __restrict__ A, const ushort* __restrict__ Whi,
    const ushort* __restrict__ Wlo, const float* __restrict__ bias,
    float* __restrict__ C)
{
    const int tid = threadIdx.x;
    const int w   = tid >> 6;
    const int lane = tid & 63;
    const int c = lane & 15;
    const int g = lane >> 4;
    const int m0 = blockIdx.x * 128 + 32 * w;

    B8u ah[2][2], al[2][2];
    #pragma unroll
    for (int rm = 0; rm < 2; ++rm) {
        const float* ap = A + (size_t)(m0 + 16 * rm + c) * 64;
        #pragma unroll
        for (int ks = 0; ks < 2; ++ks) {
            float4 v0 = *(const float4*)(ap + 32 * ks + 8 * g);
            float4 v1 = *(const float4*)(ap + 32 * ks + 8 * g + 4);
            split8(v0, v1, ah[rm][ks], al[rm][ks]);
        }
    }

    f32x4 acc[NCOLS / 16][2];
    #pragma unroll
    for (int nt = 0; nt < NCOLS / 16; ++nt) {
        float bv = bias[16 * nt + c];
        #pragma unroll
        for (int rm = 0; rm < 2; ++rm)
            acc[nt][rm] = (f32x4){bv, bv, bv, bv};
    }

    #pragma unroll
    for (int nt = 0; nt < NCOLS / 16; ++nt) {
        B8u wh[2], wl[2];
        #pragma unroll
        for (int ks = 0; ks < 2; ++ks) {
            size_t off = (size_t)(16 * nt + c) * 64 + 32 * ks + 8 * g;
            wh[ks].q = *(const uint4*)(Whi + off);
            wl[ks].q = *(const uint4*)(Wlo + off);
        }
        #pragma unroll
        for (int rm = 0; rm < 2; ++rm)
            #pragma unroll
            for (int ks = 0; ks < 2; ++ks) {
                acc[nt][rm] = __builtin_amdgcn_mfma_f32_16x16x32_bf16(ah[rm][ks].v, wh[ks].v, acc[nt][rm], 0, 0, 0);
                acc[nt][rm] = __builtin_amdgcn_mfma_f32_16x16x32_bf16(al[rm][ks].v, wh[ks].v, acc[nt][rm], 0, 0, 0);
                acc[nt][rm] = __builtin_amdgcn_mfma_f32_16x16x32_bf16(ah[rm][ks].v, wl[ks].v, acc[nt][rm], 0, 0, 0);
            }
    }

    #pragma unroll
    for (int nt = 0; nt < NCOLS / 16; ++nt)
        #pragma unroll
        for (int rm = 0; rm < 2; ++rm)
            #pragma unroll
            for (int reg = 0; reg < 4; ++reg) {
                int row = m0 + 16 * rm + 4 * g + reg;
                C[(size_t)row * NCOLS + 16 * nt + reg * 0 + c] = acc[nt][rm][reg];
            }
}

// ---------------------------------------------------------------------------
// Fused FFN via split-bf16 MFMA (unchanged from round 3)
// ---------------------------------------------------------------------------
__global__ __launch_bounds__(256, 2) void ffn_mfma(
    const float* __restrict__ Xin,
    const ushort* __restrict__ W1hi, const ushort* __restrict__ W1lo,
    const ushort* __restrict__ W2hi, const ushort* __restrict__ W2lo,
    const float* __restrict__ b1, const float* __restrict__ b2,
    float* __restrict__ Out)
{
    __shared__ __align__(16) ushort sW1h[64 * 72], sW1l[64 * 72];
    __shared__ __align__(16) ushort sW2h[64 * 72], sW2l[64 * 72];
    __shared__ __align__(16) ushort sHh[128 * 72], sHl[128 * 72];
    __shared__ float sb1[64];

    const int tid = threadIdx.x;
    const int w   = tid >> 6;
    const int lane = tid & 63;
    const int c = lane & 15;
    const int g = lane >> 4;
    const int r0 = blockIdx.x * 128;

    B8u xh[2][2], xl[2][2];
    #pragma unroll
    for (int rm = 0; rm < 2; ++rm) {
        const float* ap = Xin + (size_t)(r0 + 32 * w + 16 * rm + c) * 64;
        #pragma unroll
        for (int ks = 0; ks < 2; ++ks) {
            float4 v0 = *(const float4*)(ap + 32 * ks + 8 * g);
            float4 v1 = *(const float4*)(ap + 32 * ks + 8 * g + 4);
            split8(v0, v1, xh[rm][ks], xl[rm][ks]);
        }
    }

    f32x4 acc2[4][2];
    #pragma unroll
    for (int jt = 0; jt < 4; ++jt) {
        float bv = b2[16 * jt + c];
        #pragma unroll
        for (int mt = 0; mt < 2; ++mt)
            acc2[jt][mt] = (f32x4){bv, bv, bv, bv};
    }

    for (int nc = 0; nc < 16; ++nc) {
        __syncthreads();
        {
            const int n = tid >> 2, s = tid & 3;
            size_t s1 = (size_t)(nc * 64 + n) * 64 + s * 16;
            size_t s2 = (size_t)n * 1024 + nc * 64 + s * 16;
            int d = n * 72 + s * 16;
            *(uint4*)&sW1h[d]     = *(const uint4*)(W1hi + s1);
            *(uint4*)&sW1h[d + 8] = *(const uint4*)(W1hi + s1 + 8);
            *(uint4*)&sW1l[d]     = *(const uint4*)(W1lo + s1);
            *(uint4*)&sW1l[d + 8] = *(const uint4*)(W1lo + s1 + 8);
            *(uint4*)&sW2h[d]     = *(const uint4*)(W2hi + s2);
            *(uint4*)&sW2h[d + 8] = *(const uint4*)(W2hi + s2 + 8);
            *(uint4*)&sW2l[d]     = *(const uint4*)(W2lo + s2);
            *(uint4*)&sW2l[d + 8] = *(const uint4*)(W2lo + s2 + 8);
            if (tid < 64) sb1[tid] = b1[nc * 64 + tid];
        }
        __syncthreads();

        f32x4 acc1[4][2];
        #pragma unroll
        for (int jm = 0; jm < 4; ++jm) {
            float b0 = sb1[16 * jm + 4 * g + 0];
            float b1v = sb1[16 * jm + 4 * g + 1];
            float b2v = sb1[16 * jm + 4 * g + 2];
            float b3v = sb1[16 * jm + 4 * g + 3];
            #pragma unroll
            for (int rm = 0; rm < 2; ++rm)
                acc1[jm][rm] = (f32x4){b0, b1v, b2v, b3v};
        }
        #pragma unroll
        for (int jm = 0; jm < 4; ++jm) {
            B8u w1h[2], w1l[2];
            #pragma unroll
            for (int ks = 0; ks < 2; ++ks) {
                int off = (16 * jm + c) * 72 + 32 * ks + 8 * g;
                w1h[ks].q = *(const uint4*)&sW1h[off];
                w1l[ks].q = *(const uint4*)&sW1l[off];
            }
            #pragma unroll
            for (int rm = 0; rm < 2; ++rm)
                #pragma unroll
                for (int ks = 0; ks < 2; ++ks) {
                    acc1[jm][rm] = __builtin_amdgcn_mfma_f32_16x16x32_bf16(w1h[ks].v, xh[rm][ks].v, acc1[jm][rm], 0, 0, 0);
                    acc1[jm][rm] = __builtin_amdgcn_mfma_f32_16x16x32_bf16(w1l[ks].v, xh[rm][ks].v, acc1[jm][rm], 0, 0, 0);
                    acc1[jm][rm] = __builtin_amdgcn_mfma_f32_16x16x32_bf16(w1h[ks].v, xl[rm][ks].v, acc1[jm][rm], 0, 0, 0);
                }
        }
        #pragma unroll
        for (int jm = 0; jm < 4; ++jm)
            #pragma unroll
            for (int rm = 0; rm < 2; ++rm) {
                ushort hh[4], hl[4];
                #pragma unroll
                for (int reg = 0; reg < 4; ++reg) {
                    float hv = fmaxf(acc1[jm][rm][reg], 0.f);
                    ushort h = f2bf(hv);
                    hh[reg] = h;
                    float fh = __uint_as_float(((uint)h) << 16);
                    hl[reg] = f2bf(hv - fh);
                }
                int el = (32 * w + 16 * rm + c) * 72 + 16 * jm + 4 * g;
                *(uint2*)&sHh[el] = make_uint2((uint)hh[0] | ((uint)hh[1] << 16),
                                               (uint)hh[2] | ((uint)hh[3] << 16));
                *(uint2*)&sHl[el] = make_uint2((uint)hl[0] | ((uint)hl[1] << 16),
                                               (uint)hl[2] | ((uint)hl[3] << 16));
            }
        asm volatile("s_waitcnt lgkmcnt(0)" ::: "memory");
        __builtin_amdgcn_sched_barrier(0);

        #pragma unroll
        for (int ks = 0; ks < 2; ++ks) {
            B8u ahh[2], ahl[2], bwh[4], bwl[4];
            #pragma unroll
            for (int mt = 0; mt < 2; ++mt) {
                int el = (32 * w + 16 * mt + c) * 72 + 32 * ks + 8 * g;
                ahh[mt].q = *(const uint4*)&sHh[el];
                ahl[mt].q = *(const uint4*)&sHl[el];
            }
            #pragma unroll
            for (int jt = 0; jt < 4; ++jt) {
                int el = (16 * jt + c) * 72 + 32 * ks + 8 * g;
                bwh[jt].q = *(const uint4*)&sW2h[el];
                bwl[jt].q = *(const uint4*)&sW2l[el];
            }
            #pragma unroll
            for (int jt = 0; jt < 4; ++jt)
                #pragma unroll
                for (int mt = 0; mt < 2; ++mt) {
                    acc2[jt][mt] = __builtin_amdgcn_mfma_f32_16x16x32_bf16(ahh[mt].v, bwh[jt].v, acc2[jt][mt], 0, 0, 0);
                    acc2[jt][mt] = __builtin_amdgcn_mfma_f32_16x16x32_bf16(ahl[mt].v, bwh[jt].v, acc2[jt][mt], 0, 0, 0);
                    acc2[jt][mt] = __builtin_amdgcn_mfma_f32_16x16x32_bf16(ahh[mt].v, bwl[jt].v, acc2[jt][mt], 0, 0, 0);
                }
        }
    }

    #pragma unroll
    for (int jt = 0; jt < 4; ++jt)
        #pragma unroll
        for (int mt = 0; mt < 2; ++mt)
            #pragma unroll
            for (int reg = 0; reg < 4; ++reg) {
                int row = r0 + 32 * w + 16 * mt + 4 * g + reg;
                Out[(size_t)row * 64 + 16 * jt + c] = fmaxf(acc2[jt][mt][reg], 0.f);
            }
}

// ---------------------------------------------------------------------------
// MFMA flash attention. Block = (head, batch), 4 independent waves
// (64 queries each), no barriers. 3-pass split-bf16 MFMA throughout.
// S^T = mfma(K, Q): lane col = query -> softmax reduce = 16 lane-local ops
// + 2 shfl_xor. P packed (hi/lo bf16) to per-wave LDS [q][k] with XOR
// oct-swizzle; PV as O^T = mfma(V^T, P).
// ---------------------------------------------------------------------------
__global__ __launch_bounds__(256, 2) void attn_mfma(
    const float* __restrict__ QKV, float* __restrict__ Out)
{
    __shared__ __align__(16) ushort Ph[4][4096];
    __shared__ __align__(16) ushort Pl[4][4096];

    const int h = blockIdx.x;
    const int b = blockIdx.y;
    const int tid = threadIdx.x;
    const int w = tid >> 6;
    const int lane = tid & 63;
    const int c = lane & 15;
    const int g = lane >> 4;
    const float scale = 0.17677669529663687f; // 1/sqrt(32)

    const float* base = QKV + (size_t)b * SEQL * 192;
    ushort* phw = Ph[w];
    ushort* plw = Pl[w];

    // Q b-frags (scale folded in), persistent
    B8u qh[4], ql[4];
    #pragma unroll
    for (int qt = 0; qt < 4; ++qt) {
        const float* p = base + (size_t)(64 * w + 16 * qt + c) * 192 + h * 32 + 8 * g;
        float4 v0 = *(const float4*)p;
        float4 v1 = *(const float4*)(p + 4);
        v0.x *= scale; v0.y *= scale; v0.z *= scale; v0.w *= scale;
        v1.x *= scale; v1.y *= scale; v1.z *= scale; v1.w *= scale;
        split8(v0, v1, qh[qt], ql[qt]);
    }

    f32x4 o[2][4]; // [dt][qt], O^T accum
    #pragma unroll
    for (int dt = 0; dt < 2; ++dt)
        #pragma unroll
        for (int qt = 0; qt < 4; ++qt)
            o[dt][qt] = (f32x4){0.f, 0.f, 0.f, 0.f};
    float mrun[4] = {-1e30f, -1e30f, -1e30f, -1e30f};
    float lrun[4] = {0.f, 0.f, 0.f, 0.f};

    for (int kc = 0; kc < 4; ++kc) {
        // ---- K a-frags for this chunk ----
        B8u kh[4], kl[4];
        #pragma unroll
        for (int kt = 0; kt < 4; ++kt) {
            const float* p = base + (size_t)(kc * 64 + 16 * kt + c) * 192 + 64 + h * 32 + 8 * g;
            split8(*(const float4*)p, *(const float4*)(p + 4), kh[kt], kl[kt]);
        }
        // ---- S^T = K . Q^T (3-pass split) ----
        f32x4 st[4][4]; // [kt][qt]
        #pragma unroll
        for (int kt = 0; kt < 4; ++kt)
            #pragma unroll
            for (int qt = 0; qt < 4; ++qt)
                st[kt][qt] = (f32x4){0.f, 0.f, 0.f, 0.f};
        #pragma unroll
        for (int kt = 0; kt < 4; ++kt)
            #pragma unroll
            for (int qt = 0; qt < 4; ++qt) {
                st[kt][qt] = __builtin_amdgcn_mfma_f32_16x16x32_bf16(kh[kt].v, qh[qt].v, st[kt][qt], 0, 0, 0);
                st[kt][qt] = __builtin_amdgcn_mfma_f32_16x16x32_bf16(kl[kt].v, qh[qt].v, st[kt][qt], 0, 0, 0);
                st[kt][qt] = __builtin_amdgcn_mfma_f32_16x16x32_bf16(kh[kt].v, ql[qt].v, st[kt][qt], 0, 0, 0);
            }

        // ---- per-query online softmax over this 64-key chunk ----
        asm volatile("s_waitcnt lgkmcnt(0)" ::: "memory"); // prev chunk P reads done
        #pragma unroll
        for (int qt = 0; qt < 4; ++qt) {
            float cmax = st[0][qt][0];
            #pragma unroll
            for (int kt = 0; kt < 4; ++kt)
                #pragma unroll
                for (int r = 0; r < 4; ++r) cmax = fmaxf(cmax, st[kt][qt][r]);
            cmax = fmaxf(cmax, __shfl_xor(cmax, 16));
            cmax = fmaxf(cmax, __shfl_xor(cmax, 32));
            const float mnew = fmaxf(mrun[qt], cmax);
            const float corr = __expf(mrun[qt] - mnew);
            mrun[qt] = mnew;
            const int ql_ = 16 * qt + c;
            float csum = 0.f;
            #pragma unroll
            for (int kt = 0; kt < 4; ++kt) {
                ushort hh[4], hl[4];
                #pragma unroll
                for (int r = 0; r < 4; ++r) {
                    float pv = __expf(st[kt][qt][r] - mnew);
                    csum += pv;
                    ushort ph_ = f2bf(pv);
                    hh[r] = ph_;
                    hl[r] = f2bf(pv - __uint_as_float(((uint)ph_) << 16));
                }
                const int ow = (2 * kt + (g >> 1)) ^ (ql_ & 7);
                const int addr = ql_ * 64 + ow * 8 + (g & 1) * 4;
                *(uint2*)&phw[addr] = make_uint2((uint)hh[0] | ((uint)hh[1] << 16),
                                                 (uint)hh[2] | ((uint)hh[3] << 16));
                *(uint2*)&plw[addr] = make_uint2((uint)hl[0] | ((uint)hl[1] << 16),
                                                 (uint)hl[2] | ((uint)hl[3] << 16));
            }
            csum += __shfl_xor(csum, 16);
            csum += __shfl_xor(csum, 32);
            lrun[qt] = lrun[qt] * corr + csum;
            #pragma unroll
            for (int dt = 0; dt < 2; ++dt)
                #pragma unroll
                for (int r = 0; r < 4; ++r) o[dt][qt][r] *= corr;
        }

        // ---- V^T a-frags ----
        B8u vh[2][2], vl[2][2]; // [ks][dt]
        #pragma unroll
        for (int ks = 0; ks < 2; ++ks)
            #pragma unroll
            for (int dt = 0; dt < 2; ++dt) {
                const float* vp = base + (size_t)(kc * 64 + ks * 32 + 8 * g) * 192 + 128 + h * 32 + 16 * dt + c;
                float f0 = vp[0], f1 = vp[192], f2 = vp[384], f3 = vp[576];
                float f4 = vp[768], f5 = vp[960], f6 = vp[1152], f7 = vp[1344];
                split8(make_float4(f0, f1, f2, f3), make_float4(f4, f5, f6, f7),
                       vh[ks][dt], vl[ks][dt]);
            }

        // same-wave LDS write->read ordering
        asm volatile("s_waitcnt lgkmcnt(0)" ::: "memory");
        __builtin_amdgcn_sched_barrier(0);

        // ---- O^T += V^T . P^T (3-pass split) ----
        #pragma unroll
        for (int ks = 0; ks < 2; ++ks)
            #pragma unroll
            for (int qt = 0; qt < 4; ++qt) {
                const int ql_ = 16 * qt + c;
                const int orr = (ks * 4 + g) ^ (ql_ & 7);
                const int addr = ql_ * 64 + orr * 8;
                B8u pbh, pbl;
                pbh.q = *(const uint4*)&phw[addr];
                pbl.q = *(const uint4*)&plw[addr];
                #pragma unroll
                for (int dt = 0; dt < 2; ++dt) {
                    o[dt][qt] = __builtin_amdgcn_mfma_f32_16x16x32_bf16(vh[ks][dt].v, pbh.v, o[dt][qt], 0, 0, 0);
                    o[dt][qt] = __builtin_amdgcn_mfma_f32_16x16x32_bf16(vl[ks][dt].v, pbh.v, o[dt][qt], 0, 0, 0);
                    o[dt][qt] = __builtin_amdgcn_mfma_f32_16x16x32_bf16(vh[ks][dt].v, pbl.v, o[dt][qt], 0, 0, 0);
                }
            }
    }

    // ---- normalize + store O ----
    #pragma unroll
    for (int qt = 0; qt < 4; ++qt) {
        const float inv = 1.f / lrun[qt];
        const size_t row = (size_t)b * SEQL + 64 * w + 16 * qt + c;
        #pragma unroll
        for (int dt = 0; dt < 2; ++dt)
            #pragma unroll
            for (int r = 0; r < 4; ++r)
                Out[row * 64 + h * 32 + 16 * dt + 4 * g + r] = o[dt][qt][r] * inv;
    }
}

// ---------------------------------------------------------------------------
// out = LN(A + B) * s + bb   (row-wise over 64), one wave per row
// ---------------------------------------------------------------------------
__global__ __launch_bounds__(256) void add_ln_kernel(
    const float* __restrict__ A, const float* __restrict__ B,
    const float* __restrict__ s, const float* __restrict__ bb,
    float* __restrict__ O)
{
    const size_t row = (size_t)blockIdx.x * 4 + (threadIdx.x >> 6);
    const int lane = threadIdx.x & 63;
    float v = A[row * 64 + lane] + B[row * 64 + lane];
    float sum = v;
    #pragma unroll
    for (int off = 32; off; off >>= 1) sum += __shfl_xor(sum, off);
    const float mean = sum * (1.f / 64.f);
    const float d = v - mean;
    float sq = d * d;
    #pragma unroll
    for (int off = 32; off; off >>= 1) sq += __shfl_xor(sq, off);
    const float var = sq * (1.f / 64.f);
    O[row * 64 + lane] = d * rsqrtf(var + 1e-5f) * s[lane] + bb[lane];
}

// ---------------------------------------------------------------------------
// Head MLP over last timestep: 64 ->256 ->64 ->32 ->1 (silu x3)
// ---------------------------------------------------------------------------
__global__ __launch_bounds__(256) void head_kernel(
    const float* __restrict__ Hf,
    const float* __restrict__ fw1, const float* __restrict__ fb1,
    const float* __restrict__ fw2, const float* __restrict__ fb2,
    const float* __restrict__ fw3, const float* __restrict__ fb3,
    const float* __restrict__ fw4, const float* __restrict__ fb4,
    float* __restrict__ out)
{
    const int b = blockIdx.x;
    const int tid = threadIdx.x;
    __shared__ float t0[64], t1[256], t2[64], t3[32];
    if (tid < 64) t0[tid] = Hf[((size_t)b * SEQL + (SEQL - 1)) * 64 + tid];
    __syncthreads();
    {
        float acc = fb1[tid];
        #pragma unroll 4
        for (int k = 0; k < 64; ++k) acc += t0[k] * fw1[tid * 64 + k];
        t1[tid] = acc / (1.f + __expf(-acc));
    }
    __syncthreads();
    if (tid < 64) {
        float acc = fb2[tid];
        #pragma unroll 4
        for (int k = 0; k < 256; ++k) acc += t1[k] * fw2[tid * 256 + k];
        t2[tid] = acc / (1.f + __expf(-acc));
    }
    __syncthreads();
    if (tid < 32) {
        float acc = fb3[tid];
        #pragma unroll 4
        for (int k = 0; k < 64; ++k) acc += t2[k] * fw3[tid * 64 + k];
        t3[tid] = acc / (1.f + __expf(-acc));
    }
    __syncthreads();
    if (tid == 0) {
        float acc = fb4[0];
        #pragma unroll
        for (int k = 0; k < 32; ++k) acc += t3[k] * fw4[k];
        out[b] = acc;
    }
}

// ---------------------------------------------------------------------------
extern "C" void kernel_launch(void* const* d_in, const int* in_sizes, int n_in,
                              void* d_out, int out_size, void* d_ws, size_t ws_size,
                              hipStream_t stream) {
    const float* x     = (const float*)d_in[0];
    const float* emb   = (const float*)d_in[1];
    const float* wih0  = (const float*)d_in[2];
    const float* whh0  = (const float*)d_in[3];
    const float* bih0  = (const float*)d_in[4];
    const float* bhh0  = (const float*)d_in[5];
    const float* wih12 = (const float*)d_in[6];
    const float* whh12 = (const float*)d_in[7];
    const float* bih12 = (const float*)d_in[8];
    const float* bhh12 = (const float*)d_in[9];
    const float* in_w1 = (const float*)d_in[10];
    const float* in_b1 = (const float*)d_in[11];
    const float* out_w1= (const float*)d_in[12];
    const float* out_b1= (const float*)d_in[13];
    const float* in_w2 = (const float*)d_in[14];
    const float* in_b2 = (const float*)d_in[15];
    const float* out_w2= (const float*)d_in[16];
    const float* out_b2= (const float*)d_in[17];
    const float* ff_w1 = (const float*)d_in[18];
    const float* ff_b1 = (const float*)d_in[19];
    const float* ff_w2 = (const float*)d_in[20];
    const float* ff_b2 = (const float*)d_in[21];
    const float* ln1_s = (const float*)d_in[22];
    const float* ln1_b = (const float*)d_in[23];
    const float* ln2_s = (const float*)d_in[24];
    const float* ln2_b = (const float*)d_in[25];
    const float* ln3_s = (const float*)d_in[26];
    const float* ln3_b = (const float*)d_in[27];
    const float* ln4_s = (const float*)d_in[28];
    const float* ln4_b = (const float*)d_in[29];
    const float* fw1   = (const float*)d_in[30];
    const float* fb1   = (const float*)d_in[31];
    const float* fw2   = (const float*)d_in[32];
    const float* fb2   = (const float*)d_in[33];
    const float* fw3   = (const float*)d_in[34];
    const float* fb3   = (const float*)d_in[35];
    const float* fw4   = (const float*)d_in[36];
    const float* fb4   = (const float*)d_in[37];

    float* ws = (float*)d_ws;
    float* X  = ws;                       // 98304*192
    float* S0 = X  + (size_t)NROWS * 192; // 98304*64
    float* S1 = S0 + (size_t)NROWS * 64;
    float* S2 = S1 + (size_t)NROWS * 64;

    ushort* bf = (ushort*)(S2 + (size_t)NROWS * 64);
    ushort* ffw1hi = bf;               // 65536
    ushort* ffw1lo = ffw1hi + 65536;
    ushort* ffw2hi = ffw1lo + 65536;   // 65536
    ushort* ffw2lo = ffw2hi + 65536;
    ushort* wghi   = ffw2lo + 65536;   // 24576 (2 layers x 192 x 64)
    ushort* wglo   = wghi + 24576;
    ushort* q1hi   = wglo + 24576;     // 12288
    ushort* q1lo   = q1hi + 12288;
    ushort* q2hi   = q1lo + 12288;
    ushort* q2lo   = q2hi + 12288;
    ushort* o1hi   = q2lo + 12288;     // 4096
    ushort* o1lo   = o1hi + 4096;
    ushort* o2hi   = o1lo + 4096;
    ushort* o2lo   = o2hi + 4096;

    // ---- pre-split all MFMA weights ----
    split_kernel<<<65536 / 256, 256, 0, stream>>>(ff_w1, ffw1hi, ffw1lo, 65536);
    split_kernel<<<65536 / 256, 256, 0, stream>>>(ff_w2, ffw2hi, ffw2lo, 65536);
    split_kernel<<<24576 / 256, 256, 0, stream>>>(wih12, wghi, wglo, 24576);
    split_kernel<<<12288 / 256, 256, 0, stream>>>(in_w1, q1hi, q1lo, 12288);
    split_kernel<<<12288 / 256, 256, 0, stream>>>(in_w2, q2hi, q2lo, 12288);
    split_kernel<<<4096 / 256, 256, 0, stream>>>(out_w1, o1hi, o1lo, 4096);
    split_kernel<<<4096 / 256, 256, 0, stream>>>(out_w2, o2hi, o2lo, 4096);

    // ---- GRU stack ----
    featproj_kernel<<<NROWS / 32, 192, 0, stream>>>(x, emb, wih0, bih0, X);
    gru_kernel<<<NB, 192, 0, stream>>>(X, whh0, bhh0, S0, 0);
    gemm_mfma<192><<<NROWS / 128, 256, 0, stream>>>(S0, wghi, wglo, bih12, X);
    gru_kernel<<<NB, 192, 0, stream>>>(X, whh12, bhh12, S1, 0);
    gemm_mfma<192><<<NROWS / 128, 256, 0, stream>>>(S1, wghi + 12288, wglo + 12288, bih12 + 192, X);
    gru_kernel<<<NB, 192, 0, stream>>>(X, whh12 + 192 * 64, bhh12 + 192, S0, 1); // g (batch-major)

    // ---- Transformer block 1 ----
    gemm_mfma<192><<<NROWS / 128, 256, 0, stream>>>(S0, q1hi, q1lo, in_b1, X);
    attn_mfma<<<dim3(2, NB), 256, 0, stream>>>(X, S1);
    gemm_mfma<64><<<NROWS / 128, 256, 0, stream>>>(S1, o1hi, o1lo, out_b1, S2);
    add_ln_kernel<<<NROWS / 4, 256, 0, stream>>>(S0, S2, ln1_s, ln1_b, S1);      // h = LN(g + a)
    ffn_mfma<<<NROWS / 128, 256, 0, stream>>>(S1, ffw1hi, ffw1lo, ffw2hi, ffw2lo, ff_b1, ff_b2, S2);
    add_ln_kernel<<<NROWS / 4, 256, 0, stream>>>(S1, S2, ln2_s, ln2_b, S0);      // h = LN(h + ffn)

    // ---- Transformer block 2 ----
    gemm_mfma<192><<<NROWS / 128, 256, 0, stream>>>(S0, q2hi, q2lo, in_b2, X);
    attn_mfma<<<dim3(2, NB), 256, 0, stream>>>(X, S1);
    gemm_mfma<64><<<NROWS / 128, 256, 0, stream>>>(S1, o2hi, o2lo, out_b2, S2);
    add_ln_kernel<<<NROWS / 4, 256, 0, stream>>>(S2, S2, ln3_s, ln3_b, S1);      // h = LN(a + a)  (per reference!)
    ffn_mfma<<<NROWS / 128, 256, 0, stream>>>(S1, ffw1hi, ffw1lo, ffw2hi, ffw2lo, ff_b1, ff_b2, S2);
    add_ln_kernel<<<NROWS / 4, 256, 0, stream>>>(S1, S2, ln4_s, ln4_b, S0);      // h = LN(h + ffn)

    // ---- Head ----
    head_kernel<<<NB, 256, 0, stream>>>(S0, fw1, fb1, fw2, fb2, fw3, fb3, fw4, fb4,
                                        (float*)d_out);
    (void)in_sizes; (void)n_in; (void)out_size; (void)ws_size;
}